// Round 1
// baseline (2272.927 us; speedup 1.0000x reference)
//
#include <hip/hip_runtime.h>
#include <hip/hip_bf16.h>
#include <math.h>

// SlotAttention: B=64 N=4096 F=256 D=256 KVQ=256 H=4 S=8 DH=64 ITERS=3
// Round 1: correctness-first fp32 implementation. K/V stored bf16 (2% absmax
// threshold = bf16-tolerant), all accumulation fp32.
// Workspace need: ~306 MB.

__device__ __forceinline__ unsigned short f2bf(float f) {
  unsigned int x = __float_as_uint(f);
  x += 0x7fffu + ((x >> 16) & 1u);   // round-to-nearest-even
  return (unsigned short)(x >> 16);
}

// ---------------------------------------------------------------------------
// Kernel 1: fused LayerNorm(inputs) + K/V projection (x_hat @ wk^T, @ wv^T).
// 64 rows/block; xs[256 k][64 r] fp32 in LDS; 8 col-tiles of 64, wt[256][64].
// Dynamic LDS 128 KiB -> 1 block/CU (known round-1 bottleneck; MFMA next).
__global__ __launch_bounds__(256) void k_ln_kv(
    const float* __restrict__ xin, const float* __restrict__ lnw,
    const float* __restrict__ lnb, const float* __restrict__ wk,
    const float* __restrict__ wv, unsigned short* __restrict__ Kb,
    unsigned short* __restrict__ Vb) {
  extern __shared__ float lds[];
  float* xs = lds;             // [256][64]
  float* wt = lds + 256 * 64;  // [256][64]
  const int t = threadIdx.x;
  const long row0 = (long)blockIdx.x * 64;
  const int r = t >> 2;
  const int q4 = t & 3;

  // load 64 rows x 256, compute LN stats (4 lanes per row), store transposed
  float4 v[16];
  float s = 0.f, ss = 0.f;
  const float4* xrow = (const float4*)(xin + (row0 + r) * 256 + q4 * 64);
#pragma unroll
  for (int i = 0; i < 16; ++i) {
    v[i] = xrow[i];
    s += v[i].x + v[i].y + v[i].z + v[i].w;
    ss += v[i].x * v[i].x + v[i].y * v[i].y + v[i].z * v[i].z + v[i].w * v[i].w;
  }
  s += __shfl_xor(s, 1);
  s += __shfl_xor(s, 2);
  ss += __shfl_xor(ss, 1);
  ss += __shfl_xor(ss, 2);
  const float mean = s * (1.f / 256.f);
  const float rstd = rsqrtf(ss * (1.f / 256.f) - mean * mean + 1e-5f);
#pragma unroll
  for (int i = 0; i < 16; ++i) {
    const int f0 = q4 * 64 + i * 4;
    const float4 w4 = *(const float4*)(lnw + f0);
    const float4 b4 = *(const float4*)(lnb + f0);
    xs[(f0 + 0) * 64 + r] = (v[i].x - mean) * rstd * w4.x + b4.x;
    xs[(f0 + 1) * 64 + r] = (v[i].y - mean) * rstd * w4.y + b4.y;
    xs[(f0 + 2) * 64 + r] = (v[i].z - mean) * rstd * w4.z + b4.z;
    xs[(f0 + 3) * 64 + r] = (v[i].w - mean) * rstd * w4.w + b4.w;
  }

  const int tc = (t & 15) * 4;   // col offset (lane-contiguous -> coalesced C)
  const int tr = (t >> 4) * 4;   // row offset

  for (int ct = 0; ct < 8; ++ct) {
    __syncthreads();
    {  // stage weight tile transposed: wt[k][c]
      const float* W = (ct < 4) ? wk : wv;
      const int cbase = (ct & 3) * 64;
      const int c = t >> 2;
      const float4* wrow = (const float4*)(W + (cbase + c) * 256 + q4 * 64);
#pragma unroll
      for (int i = 0; i < 16; ++i) {
        const float4 w4 = wrow[i];
        const int f0 = q4 * 64 + i * 4;
        wt[(f0 + 0) * 64 + c] = w4.x;
        wt[(f0 + 1) * 64 + c] = w4.y;
        wt[(f0 + 2) * 64 + c] = w4.z;
        wt[(f0 + 3) * 64 + c] = w4.w;
      }
    }
    __syncthreads();
    float acc[4][4] = {};
#pragma unroll 4
    for (int k = 0; k < 256; ++k) {
      const float4 a4 = *(const float4*)(xs + k * 64 + tr);
      const float4 w4 = *(const float4*)(wt + k * 64 + tc);
      const float av[4] = {a4.x, a4.y, a4.z, a4.w};
      const float wv4[4] = {w4.x, w4.y, w4.z, w4.w};
#pragma unroll
      for (int i = 0; i < 4; ++i)
#pragma unroll
        for (int j = 0; j < 4; ++j) acc[i][j] += av[i] * wv4[j];
    }
    unsigned short* Out = (ct < 4) ? Kb : Vb;
    const int cg = (ct & 3) * 64 + tc;
#pragma unroll
    for (int i = 0; i < 4; ++i) {
      uint2 p;
      p.x = (unsigned int)f2bf(acc[i][0]) | ((unsigned int)f2bf(acc[i][1]) << 16);
      p.y = (unsigned int)f2bf(acc[i][2]) | ((unsigned int)f2bf(acc[i][3]) << 16);
      *(uint2*)(Out + (row0 + tr + i) * 256 + cg) = p;
    }
  }
}

// ---------------------------------------------------------------------------
// Kernel 0b: transpose gru_wih, gru_whh, wq for coalesced reads.
__global__ void k_transpose(const float* __restrict__ wih,
                            const float* __restrict__ whh,
                            const float* __restrict__ wqs,
                            float* __restrict__ wihT, float* __restrict__ whhT,
                            float* __restrict__ wqT) {
  const int idx = blockIdx.x * 256 + threadIdx.x;
  if (idx < 768 * 256) {
    const int g = idx >> 8, k = idx & 255;
    wihT[k * 768 + g] = wih[idx];
  } else if (idx < 2 * 768 * 256) {
    const int j = idx - 768 * 256;
    const int g = j >> 8, k = j & 255;
    whhT[k * 768 + g] = whh[j];
  } else {
    const int j = idx - 2 * 768 * 256;
    const int c = j >> 8, k = j & 255;
    wqT[k * 256 + c] = wqs[j];
  }
}

// ---------------------------------------------------------------------------
// Kernel 2: LN(slots) + q = sn @ wq^T.  One block per b (8 rows x 256 cols).
__global__ __launch_bounds__(256) void k_q(
    const float* __restrict__ slots, const float* __restrict__ lnw,
    const float* __restrict__ lnb, const float* __restrict__ wqT,
    float* __restrict__ qout) {
  __shared__ float sl[8 * 256];
  __shared__ float mstat[8], rstat[8];
  const int b = blockIdx.x, t = threadIdx.x;
#pragma unroll
  for (int i = 0; i < 8; ++i) sl[i * 256 + t] = slots[b * 2048 + i * 256 + t];
  __syncthreads();
  if (t < 8) {
    float s = 0.f, ss = 0.f;
    for (int k = 0; k < 256; ++k) {
      const float x = sl[t * 256 + k];
      s += x;
      ss += x * x;
    }
    const float m = s * (1.f / 256.f);
    mstat[t] = m;
    rstat[t] = rsqrtf(ss * (1.f / 256.f) - m * m + 1e-5f);
  }
  __syncthreads();
  const float w = lnw[t], bb = lnb[t];
#pragma unroll
  for (int i = 0; i < 8; ++i)
    sl[i * 256 + t] = (sl[i * 256 + t] - mstat[i]) * rstat[i] * w + bb;
  __syncthreads();
  float acc[8] = {};
  for (int k = 0; k < 256; k += 4) {
    const float w0 = wqT[(k + 0) * 256 + t];
    const float w1 = wqT[(k + 1) * 256 + t];
    const float w2 = wqT[(k + 2) * 256 + t];
    const float w3 = wqT[(k + 3) * 256 + t];
#pragma unroll
    for (int i = 0; i < 8; ++i) {
      const float4 x4 = *(const float4*)(sl + i * 256 + k);
      acc[i] += x4.x * w0 + x4.y * w1 + x4.z * w2 + x4.w * w3;
    }
  }
#pragma unroll
  for (int i = 0; i < 8; ++i) qout[b * 2048 + i * 256 + t] = acc[i];
}

// ---------------------------------------------------------------------------
// Kernel 3: dots = q.k * SCALE, inverted softmax over the 32 (i,h) per column,
// store attn_pre[b][ih][j], per-tile rowsum partials, (last iter) attn_out.
// Grid (8 j-tiles, 64 b); 512 cols per block in 8 chunks of 64.
// K chunk staged in LDS with XOR-swizzle (T2) for conflict-free b128 reads.
template <bool LAST>
__global__ __launch_bounds__(256) void k_attn(
    const float* __restrict__ qin, const unsigned short* __restrict__ Kb,
    float* __restrict__ attn_pre, float* __restrict__ rowsum_part,
    float* __restrict__ attn_out) {
  __shared__ float qs[32 * 64];
  __shared__ unsigned short ks[64 * 256];
  __shared__ float dsm[64 * 33];
  const int t = threadIdx.x;
  const int jt = blockIdx.x;
  const int b = blockIdx.y;
#pragma unroll
  for (int i = 0; i < 8; ++i) qs[i * 256 + t] = qin[b * 2048 + i * 256 + t];

  const int jq = t & 15;
  const int hp = (t >> 4) & 3;
  const int ih2 = t >> 6;  // i in {2*ih2, 2*ih2+1}
  float rsacc[32];
#pragma unroll
  for (int c = 0; c < 32; ++c) rsacc[c] = 0.f;

  for (int ch = 0; ch < 8; ++ch) {
    __syncthreads();
    const long j0 = (long)jt * 512 + ch * 64;
    // stage 64 rows x 256 bf16, swizzled
#pragma unroll
    for (int i = 0; i < 8; ++i) {
      const int idx = t + 256 * i;
      const int j = idx >> 5;
      const int c16 = idx & 31;
      const uint4 val =
          *(const uint4*)(Kb + ((long)b * 4096 + j0 + j) * 256 + c16 * 8);
      *(uint4*)((char*)ks + j * 512 + ((c16 * 16) ^ ((j & 7) << 4))) = val;
    }
    __syncthreads();
    float acc[2][4] = {};
#pragma unroll
    for (int g = 0; g < 8; ++g) {
      float kf[4][8];
#pragma unroll
      for (int jj = 0; jj < 4; ++jj) {
        const int j = jq + jj * 16;
        const int slot = (((hp * 8 + g) << 4)) ^ ((j & 7) << 4);
        const uint4 kv = *(const uint4*)((const char*)ks + j * 512 + slot);
        kf[jj][0] = __uint_as_float(kv.x << 16);
        kf[jj][1] = __uint_as_float(kv.x & 0xffff0000u);
        kf[jj][2] = __uint_as_float(kv.y << 16);
        kf[jj][3] = __uint_as_float(kv.y & 0xffff0000u);
        kf[jj][4] = __uint_as_float(kv.z << 16);
        kf[jj][5] = __uint_as_float(kv.z & 0xffff0000u);
        kf[jj][6] = __uint_as_float(kv.w << 16);
        kf[jj][7] = __uint_as_float(kv.w & 0xffff0000u);
      }
#pragma unroll
      for (int ii = 0; ii < 2; ++ii) {
        const int ih = (ih2 * 2 + ii) * 4 + hp;
        const float4 qa = *(const float4*)(qs + ih * 64 + g * 8);
        const float4 qb = *(const float4*)(qs + ih * 64 + g * 8 + 4);
#pragma unroll
        for (int jj = 0; jj < 4; ++jj) {
          acc[ii][jj] += qa.x * kf[jj][0] + qa.y * kf[jj][1] +
                         qa.z * kf[jj][2] + qa.w * kf[jj][3] +
                         qb.x * kf[jj][4] + qb.y * kf[jj][5] +
                         qb.z * kf[jj][6] + qb.w * kf[jj][7];
        }
      }
    }
#pragma unroll
    for (int ii = 0; ii < 2; ++ii) {
      const int ih = (ih2 * 2 + ii) * 4 + hp;
#pragma unroll
      for (int jj = 0; jj < 4; ++jj)
        dsm[(jq + jj * 16) * 33 + ih] = acc[ii][jj] * 0.125f;
    }
    __syncthreads();
    if (t < 64) {  // column softmax over the 32 (i,h) values
      float vals[32];
      float mx = -1e30f;
#pragma unroll
      for (int c = 0; c < 32; ++c) {
        vals[c] = dsm[t * 33 + c];
        mx = fmaxf(mx, vals[c]);
      }
      float sum = 0.f;
#pragma unroll
      for (int c = 0; c < 32; ++c) {
        vals[c] = __expf(vals[c] - mx);
        sum += vals[c];
      }
      const float inv = 1.f / sum;
      const long jg = j0 + t;
#pragma unroll
      for (int c = 0; c < 32; ++c) {
        const float a = vals[c] * inv;
        rsacc[c] += a;
        attn_pre[((long)(b * 32 + c)) * 4096 + jg] = a;
      }
      if (LAST) {
#pragma unroll
        for (int i = 0; i < 8; ++i) {
          attn_out[((long)(b * 8 + i)) * 4096 + jg] =
              (vals[4 * i] + vals[4 * i + 1] + vals[4 * i + 2] +
               vals[4 * i + 3]) *
              inv * 0.25f;
        }
      }
    }
  }
  if (t < 64) {  // deterministic per-tile rowsum partials (no atomics)
#pragma unroll
    for (int c = 0; c < 32; ++c) {
      float vv = rsacc[c];
      vv += __shfl_xor(vv, 1);
      vv += __shfl_xor(vv, 2);
      vv += __shfl_xor(vv, 4);
      vv += __shfl_xor(vv, 8);
      vv += __shfl_xor(vv, 16);
      vv += __shfl_xor(vv, 32);
      if (t == 0) rowsum_part[(jt * 64 + b) * 32 + c] = vv;
    }
  }
}

// ---------------------------------------------------------------------------
// Kernel 4: raw update sums: upart[js] = sum_j attn_pre*v, svpart[js] = sum_j v
// (EPS renorm applied later: upd = rs*(p + EPS*sv)). Grid (8 = h + 4*js, 64 b).
__global__ __launch_bounds__(256) void k_upd(
    const float* __restrict__ attn_pre, const unsigned short* __restrict__ Vb,
    float* __restrict__ upart, float* __restrict__ svpart) {
  __shared__ float red[8 * 8 * 64];
  __shared__ float svred[8 * 64];
  const int t = threadIdx.x;
  const int h = blockIdx.x & 3;
  const int js = blockIdx.x >> 2;
  const int b = blockIdx.y;
  const int d2 = t & 31;
  const int jg = t >> 5;
  const long jbase = (long)js * 2048 + jg * 256;
  float acc[8][2] = {};
  float sv0 = 0.f, sv1 = 0.f;
  const unsigned short* vp =
      Vb + ((long)b * 4096 + jbase) * 256 + h * 64 + d2 * 2;
  for (int jj = 0; jj < 256; jj += 4) {
    float4 a4[8];
#pragma unroll
    for (int i = 0; i < 8; ++i)
      a4[i] = *(const float4*)(attn_pre +
                               ((long)(b * 32 + i * 4 + h)) * 4096 + jbase + jj);
#pragma unroll
    for (int u = 0; u < 4; ++u) {
      const unsigned int vu = *(const unsigned int*)(vp + (jj + u) * 256);
      const float vf0 = __uint_as_float(vu << 16);
      const float vf1 = __uint_as_float(vu & 0xffff0000u);
      sv0 += vf0;
      sv1 += vf1;
#pragma unroll
      for (int i = 0; i < 8; ++i) {
        const float a = ((const float*)&a4[i])[u];
        acc[i][0] += a * vf0;
        acc[i][1] += a * vf1;
      }
    }
  }
#pragma unroll
  for (int i = 0; i < 8; ++i) {
    float2 p2;
    p2.x = acc[i][0];
    p2.y = acc[i][1];
    *(float2*)(&red[(jg * 8 + i) * 64 + d2 * 2]) = p2;
  }
  float2 sv2;
  sv2.x = sv0;
  sv2.y = sv1;
  *(float2*)(&svred[jg * 64 + d2 * 2]) = sv2;
  __syncthreads();
#pragma unroll
  for (int o = 0; o < 2; ++o) {
    const int oidx = t + o * 256;
    const int i = oidx >> 6, d = oidx & 63;
    float ssum = 0.f;
#pragma unroll
    for (int g2 = 0; g2 < 8; ++g2) ssum += red[(g2 * 8 + i) * 64 + d];
    upart[(long)js * 512 * 256 + ((long)(b * 8 + i)) * 256 + h * 64 + d] = ssum;
  }
  if (t < 64) {
    float ssum = 0.f;
#pragma unroll
    for (int g2 = 0; g2 < 8; ++g2) ssum += svred[g2 * 64 + t];
    svpart[js * (64 * 256) + b * 256 + h * 64 + t] = ssum;
  }
}

// ---------------------------------------------------------------------------
// Kernel 5: GRU cell, one block per b (8 rows). torch gate order r,z,n.
template <bool LAST>
__global__ __launch_bounds__(256) void k_gru(
    const float* __restrict__ upart, const float* __restrict__ svpart,
    const float* __restrict__ rowsum_part, const float* __restrict__ wihT,
    const float* __restrict__ whhT, const float* __restrict__ bih,
    const float* __restrict__ bhh, float* __restrict__ slots,
    float* __restrict__ dout) {
  __shared__ float xl[8 * 256];
  __shared__ float hl[8 * 256];
  __shared__ float rs[32];
  const int t = threadIdx.x;
  const int b = blockIdx.x;
  if (t < 32) {
    float s2 = 0.f;
#pragma unroll
    for (int jt = 0; jt < 8; ++jt) s2 += rowsum_part[(jt * 64 + b) * 32 + t];
    rs[t] = 1.f / (s2 + 4096.f * 1e-8f);
  }
  __syncthreads();
  const float svs = svpart[b * 256 + t] + svpart[64 * 256 + b * 256 + t];
  const int hcol = t >> 6;
#pragma unroll
  for (int r = 0; r < 8; ++r) {
    const float p = upart[(b * 8 + r) * 256 + t] +
                    upart[512 * 256 + (b * 8 + r) * 256 + t];
    xl[r * 256 + t] = (p + 1e-8f * svs) * rs[r * 4 + hcol];
    hl[r * 256 + t] = slots[b * 2048 + r * 256 + t];
  }
  __syncthreads();
  float air[8] = {}, aiz[8] = {}, ain[8] = {};
  float ahr[8] = {}, ahz[8] = {}, ahn[8] = {};
  for (int k = 0; k < 256; k += 4) {
    float wir[4], wiz[4], win_[4], whr[4], whz[4], whn[4];
#pragma unroll
    for (int u = 0; u < 4; ++u) {
      wir[u] = wihT[(k + u) * 768 + t];
      wiz[u] = wihT[(k + u) * 768 + 256 + t];
      win_[u] = wihT[(k + u) * 768 + 512 + t];
      whr[u] = whhT[(k + u) * 768 + t];
      whz[u] = whhT[(k + u) * 768 + 256 + t];
      whn[u] = whhT[(k + u) * 768 + 512 + t];
    }
#pragma unroll
    for (int r = 0; r < 8; ++r) {
      const float4 x4 = *(const float4*)(xl + r * 256 + k);
      const float4 h4 = *(const float4*)(hl + r * 256 + k);
      air[r] += x4.x * wir[0] + x4.y * wir[1] + x4.z * wir[2] + x4.w * wir[3];
      aiz[r] += x4.x * wiz[0] + x4.y * wiz[1] + x4.z * wiz[2] + x4.w * wiz[3];
      ain[r] += x4.x * win_[0] + x4.y * win_[1] + x4.z * win_[2] + x4.w * win_[3];
      ahr[r] += h4.x * whr[0] + h4.y * whr[1] + h4.z * whr[2] + h4.w * whr[3];
      ahz[r] += h4.x * whz[0] + h4.y * whz[1] + h4.z * whz[2] + h4.w * whz[3];
      ahn[r] += h4.x * whn[0] + h4.y * whn[1] + h4.z * whn[2] + h4.w * whn[3];
    }
  }
  const float bir = bih[t], biz = bih[256 + t], bin_ = bih[512 + t];
  const float bhr = bhh[t], bhz = bhh[256 + t], bhn = bhh[512 + t];
#pragma unroll
  for (int r = 0; r < 8; ++r) {
    const float rr = 1.f / (1.f + __expf(-(air[r] + bir + ahr[r] + bhr)));
    const float zz = 1.f / (1.f + __expf(-(aiz[r] + biz + ahz[r] + bhz)));
    const float nn2 = tanhf(ain[r] + bin_ + rr * (ahn[r] + bhn));
    const float hn = (1.f - zz) * nn2 + zz * hl[r * 256 + t];
    slots[b * 2048 + r * 256 + t] = hn;
    if (LAST) dout[b * 2048 + r * 256 + t] = hn;
  }
}

// ---------------------------------------------------------------------------
extern "C" void kernel_launch(void* const* d_in, const int* in_sizes, int n_in,
                              void* d_out, int out_size, void* d_ws,
                              size_t ws_size, hipStream_t stream) {
  const float* xin = (const float*)d_in[0];
  const float* cond = (const float*)d_in[1];
  const float* lnin_w = (const float*)d_in[2];
  const float* lnin_b = (const float*)d_in[3];
  const float* lns_w = (const float*)d_in[4];
  const float* lns_b = (const float*)d_in[5];
  const float* wq = (const float*)d_in[6];
  const float* wk = (const float*)d_in[7];
  const float* wv = (const float*)d_in[8];
  const float* gwih = (const float*)d_in[9];
  const float* gwhh = (const float*)d_in[10];
  const float* gbih = (const float*)d_in[11];
  const float* gbhh = (const float*)d_in[12];
  float* out = (float*)d_out;

  char* ws = (char*)d_ws;
  unsigned short* Kb = (unsigned short*)ws;  ws += 64l * 4096 * 256 * 2;
  unsigned short* Vb = (unsigned short*)ws;  ws += 64l * 4096 * 256 * 2;
  float* attn_pre = (float*)ws;              ws += 64l * 32 * 4096 * 4;
  float* upart = (float*)ws;                 ws += 2l * 512 * 256 * 4;
  float* svpart = (float*)ws;                ws += 2l * 64 * 256 * 4;
  float* rowsum_part = (float*)ws;           ws += 8l * 64 * 32 * 4;
  float* qbuf = (float*)ws;                  ws += 512l * 256 * 4;
  float* slots = (float*)ws;                 ws += 512l * 256 * 4;
  float* wihT = (float*)ws;                  ws += 256l * 768 * 4;
  float* whhT = (float*)ws;                  ws += 256l * 768 * 4;
  float* wqT = (float*)ws;                   ws += 256l * 256 * 4;
  // total ~306 MB

  hipMemcpyAsync(slots, cond, 512 * 256 * 4, hipMemcpyDeviceToDevice, stream);
  k_transpose<<<1792, 256, 0, stream>>>(gwih, gwhh, wq, wihT, whhT, wqT);
  (void)hipFuncSetAttribute(reinterpret_cast<const void*>(&k_ln_kv),
                            hipFuncAttributeMaxDynamicSharedMemorySize, 131072);
  k_ln_kv<<<4096, 256, 131072, stream>>>(xin, lnin_w, lnin_b, wk, wv, Kb, Vb);

  for (int it = 0; it < 3; ++it) {
    k_q<<<64, 256, 0, stream>>>(slots, lns_w, lns_b, wqT, qbuf);
    if (it == 2)
      k_attn<true><<<dim3(8, 64), 256, 0, stream>>>(qbuf, Kb, attn_pre,
                                                    rowsum_part, out + 131072);
    else
      k_attn<false><<<dim3(8, 64), 256, 0, stream>>>(qbuf, Kb, attn_pre,
                                                     rowsum_part, out + 131072);
    k_upd<<<dim3(8, 64), 256, 0, stream>>>(attn_pre, Vb, upart, svpart);
    if (it == 2)
      k_gru<true><<<64, 256, 0, stream>>>(upart, svpart, rowsum_part, wihT,
                                          whhT, gbih, gbhh, slots, out);
    else
      k_gru<false><<<64, 256, 0, stream>>>(upart, svpart, rowsum_part, wihT,
                                           whhT, gbih, gbhh, slots, out);
  }
}

// Round 2
// 803.012 us; speedup vs baseline: 2.8305x; 2.8305x over previous
//
#include <hip/hip_runtime.h>
#include <hip/hip_bf16.h>
#include <math.h>

// SlotAttention: B=64 N=4096 F=256 D=256 KVQ=256 H=4 S=8 DH=64 ITERS=3
// Round 2: MFMA projection GEMM with LN folded into epilogue affine;
// fused attn(dots+inverted-softmax+PV+rowsum) kernel; bf16 K/V.

using frag_ab = __attribute__((ext_vector_type(8))) short;   // 8 bf16
using f32x4  = __attribute__((ext_vector_type(4))) float;

__device__ __forceinline__ unsigned short f2bf(float f) {
  unsigned int x = __float_as_uint(f);
  x += 0x7fffu + ((x >> 16) & 1u);   // RNE
  return (unsigned short)(x >> 16);
}
__device__ __forceinline__ float bflo(unsigned int u) { return __uint_as_float(u << 16); }
__device__ __forceinline__ float bfhi(unsigned int u) { return __uint_as_float(u & 0xffff0000u); }

// ---------------------------------------------------------------------------
// LN row stats: one wave per row (64 lanes x float4). stats[row] = (mean, rstd)
__global__ __launch_bounds__(256) void k_stats(const float* __restrict__ xin,
                                               float2* __restrict__ stats) {
  const int lane = threadIdx.x & 63;
  const long row = (long)blockIdx.x * 4 + (threadIdx.x >> 6);
  const float4 v = *(const float4*)(xin + row * 256 + lane * 4);
  float s = v.x + v.y + v.z + v.w;
  float ss = v.x * v.x + v.y * v.y + v.z * v.z + v.w * v.w;
#pragma unroll
  for (int m = 1; m < 64; m <<= 1) {
    s += __shfl_xor(s, m);
    ss += __shfl_xor(ss, m);
  }
  const float mean = s * (1.f / 256.f);
  const float rstd = rsqrtf(ss * (1.f / 256.f) - mean * mean + 1e-5f);
  if (lane == 0) stats[row] = make_float2(mean, rstd);
}

// ---------------------------------------------------------------------------
// Weight prep: Wp[n][k] = bf16(W[n][k]*lnw[k]); c12[n]=sum(b*W), c12[512+n]=sum(w*W)
// W rows: n<256 -> wk[n], else wv[n-256]. One wave per n.
__global__ __launch_bounds__(256) void k_wprep(
    const float* __restrict__ wk, const float* __restrict__ wv,
    const float* __restrict__ lnw, const float* __restrict__ lnb,
    unsigned short* __restrict__ Wp, float* __restrict__ c12) {
  const int lane = threadIdx.x & 63;
  const int n = blockIdx.x * 4 + (threadIdx.x >> 6);
  const float* W = (n < 256) ? (wk + n * 256) : (wv + (long)(n - 256) * 256);
  const float4 w4 = *(const float4*)(W + lane * 4);
  const float4 g4 = *(const float4*)(lnw + lane * 4);
  const float4 b4 = *(const float4*)(lnb + lane * 4);
  float c1 = w4.x * b4.x + w4.y * b4.y + w4.z * b4.z + w4.w * b4.w;
  float c2 = w4.x * g4.x + w4.y * g4.y + w4.z * g4.z + w4.w * g4.w;
  uint2 o;
  o.x = (unsigned)f2bf(w4.x * g4.x) | ((unsigned)f2bf(w4.y * g4.y) << 16);
  o.y = (unsigned)f2bf(w4.z * g4.z) | ((unsigned)f2bf(w4.w * g4.w) << 16);
  *(uint2*)(Wp + n * 256 + lane * 4) = o;
#pragma unroll
  for (int m = 1; m < 64; m <<= 1) {
    c1 += __shfl_xor(c1, m);
    c2 += __shfl_xor(c2, m);
  }
  if (lane == 0) {
    c12[n] = c1;
    c12[512 + n] = c2;
  }
}

// ---------------------------------------------------------------------------
// transpose gru weights + wq (fp32, tiny)
__global__ void k_transpose(const float* __restrict__ wih,
                            const float* __restrict__ whh,
                            const float* __restrict__ wqs,
                            float* __restrict__ wihT, float* __restrict__ whhT,
                            float* __restrict__ wqT) {
  const int idx = blockIdx.x * 256 + threadIdx.x;
  if (idx < 768 * 256) {
    const int g = idx >> 8, k = idx & 255;
    wihT[k * 768 + g] = wih[idx];
  } else if (idx < 2 * 768 * 256) {
    const int j = idx - 768 * 256;
    const int g = j >> 8, k = j & 255;
    whhT[k * 768 + g] = whh[j];
  } else {
    const int j = idx - 2 * 768 * 256;
    const int c = j >> 8, k = j & 255;
    wqT[k * 256 + c] = wqs[j];
  }
}

// ---------------------------------------------------------------------------
// Projection GEMM: C[262144x512] = bf16(x)[262144x256] @ Wp^T, epilogue applies
// LN affine: out = rstd*acc + c1 - mean*rstd*c2, written bf16 to Kb/Vb.
// BM=128 BN=128 BK=64, 256 thr (4 waves 2x2), 16x16x32 bf16 MFMA.
__global__ __launch_bounds__(256) void k_gemm(
    const float* __restrict__ xin, const float2* __restrict__ stats,
    const unsigned short* __restrict__ Wp, const float* __restrict__ c12,
    unsigned short* __restrict__ Kb, unsigned short* __restrict__ Vb) {
  __shared__ __align__(16) char sh[32768];       // As 16K | Bs 16K; reused as out tile
  __shared__ float2 stats_s[128];
  unsigned short* As = (unsigned short*)sh;              // [128 r][64 k]
  unsigned short* Bs = (unsigned short*)(sh + 16384);    // [128 n][64 k]
  const int t = threadIdx.x;
  // bijective XCD-chunk swizzle (8192 blocks, 8 XCDs)
  const int id = blockIdx.x;
  const int work = (id & 7) * 1024 + (id >> 3);
  const int mblk = work >> 2, nblk = work & 3;
  const long row0 = (long)mblk * 128;
  const int n0 = nblk * 128;
  const int lane = t & 63, w = t >> 6;
  const int wm = w >> 1, wn = w & 1;

  if (t < 128) stats_s[t] = stats[row0 + t];

  f32x4 acc[4][4];
#pragma unroll
  for (int m = 0; m < 4; ++m)
#pragma unroll
    for (int n = 0; n < 4; ++n) acc[m][n] = (f32x4){0.f, 0.f, 0.f, 0.f};

  for (int ks = 0; ks < 4; ++ks) {
    if (ks) __syncthreads();
    // stage A: load fp32, cvt bf16, ds_write_b128. LDS o = rnd*4096 + t*16.
#pragma unroll
    for (int rnd = 0; rnd < 4; ++rnd) {
      const int o = rnd * 4096 + t * 16;
      const int r = o >> 7, kb = o & 127;
      const float4* src =
          (const float4*)((const char*)xin + (row0 + r) * 1024 + ks * 256 + kb * 2);
      const float4 x0 = src[0];
      const float4 x1 = src[1];
      uint4 p;
      p.x = (unsigned)f2bf(x0.x) | ((unsigned)f2bf(x0.y) << 16);
      p.y = (unsigned)f2bf(x0.z) | ((unsigned)f2bf(x0.w) << 16);
      p.z = (unsigned)f2bf(x1.x) | ((unsigned)f2bf(x1.y) << 16);
      p.w = (unsigned)f2bf(x1.z) | ((unsigned)f2bf(x1.w) << 16);
      *(uint4*)((char*)As + o) = p;
    }
    // stage B via global_load_lds (bf16 already)
#pragma unroll
    for (int rnd = 0; rnd < 4; ++rnd) {
      const int o = rnd * 4096 + t * 16;
      const int n = o >> 7, kb = o & 127;
      __builtin_amdgcn_global_load_lds(
          (const unsigned int*)((const char*)Wp + (n0 + n) * 512 + ks * 128 + kb),
          (unsigned int*)((char*)Bs + o), 16, 0, 0);
    }
    __syncthreads();
#pragma unroll
    for (int kk = 0; kk < 2; ++kk) {
      frag_ab af[4], bf[4];
#pragma unroll
      for (int m = 0; m < 4; ++m)
        af[m] = *(const frag_ab*)((const char*)As +
                                  (wm * 64 + m * 16 + (lane & 15)) * 128 +
                                  kk * 64 + (lane >> 4) * 16);
#pragma unroll
      for (int n = 0; n < 4; ++n)
        bf[n] = *(const frag_ab*)((const char*)Bs +
                                  (wn * 64 + n * 16 + (lane & 15)) * 128 +
                                  kk * 64 + (lane >> 4) * 16);
#pragma unroll
      for (int m = 0; m < 4; ++m)
#pragma unroll
        for (int n = 0; n < 4; ++n)
          acc[m][n] =
              __builtin_amdgcn_mfma_f32_16x16x32_bf16(af[m], bf[n], acc[m][n], 0, 0, 0);
    }
  }
  __syncthreads();
  // epilogue: LN affine + repack through LDS (XOR swizzle on bits 5-6 by row>>2)
#pragma unroll
  for (int m = 0; m < 4; ++m)
#pragma unroll
    for (int n = 0; n < 4; ++n) {
      const int C = wn * 64 + n * 16 + (lane & 15);
      const int gn = n0 + C;
      const float c1v = c12[gn];
      const float c2v = c12[512 + gn];
#pragma unroll
      for (int r = 0; r < 4; ++r) {
        const int R = wm * 64 + m * 16 + (lane >> 4) * 4 + r;
        const float2 ms = stats_s[R];
        const float val = ms.y * acc[m][n][r] + (c1v - ms.x * ms.y * c2v);
        int o = R * 256 + C * 2;
        o ^= ((R >> 2) & 3) << 5;
        *(unsigned short*)(sh + o) = f2bf(val);
      }
    }
  __syncthreads();
  unsigned short* Out = (nblk < 2) ? Kb : Vb;
  const int gc0 = (nblk & 1) * 128;
#pragma unroll
  for (int p = 0; p < 8; ++p) {
    const int R = p * 16 + (t >> 4);
    int o = R * 256 + (t & 15) * 16;
    o ^= ((R >> 2) & 3) << 5;
    const uint4 val = *(const uint4*)(sh + o);
    *(uint4*)(Out + (row0 + R) * 256 + gc0 + (t & 15) * 8) = val;
  }
}

// ---------------------------------------------------------------------------
// LN(slots) + q = sn @ wq^T. One block per b.
__global__ __launch_bounds__(256) void k_q(
    const float* __restrict__ slots, const float* __restrict__ lnw,
    const float* __restrict__ lnb, const float* __restrict__ wqT,
    float* __restrict__ qout) {
  __shared__ float sl[8 * 256];
  __shared__ float mstat[8], rstat[8];
  const int b = blockIdx.x, t = threadIdx.x;
#pragma unroll
  for (int i = 0; i < 8; ++i) sl[i * 256 + t] = slots[b * 2048 + i * 256 + t];
  __syncthreads();
  if (t < 8) {
    float s = 0.f, ss = 0.f;
    for (int k = 0; k < 256; ++k) {
      const float x = sl[t * 256 + k];
      s += x;
      ss += x * x;
    }
    const float m = s * (1.f / 256.f);
    mstat[t] = m;
    rstat[t] = rsqrtf(ss * (1.f / 256.f) - m * m + 1e-5f);
  }
  __syncthreads();
  const float w = lnw[t], bb = lnb[t];
#pragma unroll
  for (int i = 0; i < 8; ++i)
    sl[i * 256 + t] = (sl[i * 256 + t] - mstat[i]) * rstat[i] * w + bb;
  __syncthreads();
  float acc[8] = {};
  for (int k = 0; k < 256; k += 4) {
    const float w0 = wqT[(k + 0) * 256 + t];
    const float w1 = wqT[(k + 1) * 256 + t];
    const float w2 = wqT[(k + 2) * 256 + t];
    const float w3 = wqT[(k + 3) * 256 + t];
#pragma unroll
    for (int i = 0; i < 8; ++i) {
      const float4 x4 = *(const float4*)(sl + i * 256 + k);
      acc[i] += x4.x * w0 + x4.y * w1 + x4.z * w2 + x4.w * w3;
    }
  }
#pragma unroll
  for (int i = 0; i < 8; ++i) qout[b * 2048 + i * 256 + t] = acc[i];
}

// ---------------------------------------------------------------------------
// Fused attention: per block (jt,b): 256 j's in 8 chunks of 32.
// dots -> column softmax over 32 (i,h) -> PV accumulate + rowsum partials.
template <bool LAST>
__global__ __launch_bounds__(256) void k_att(
    const float* __restrict__ qin, const unsigned short* __restrict__ Kb,
    const unsigned short* __restrict__ Vb, float* __restrict__ upart,
    float* __restrict__ svpart, float* __restrict__ rowsum_part,
    float* __restrict__ attn_out) {
  __shared__ float qs[2048];                       // [i][h*64+d]
  __shared__ __align__(16) unsigned short ks[32 * 256];  // swizzled K chunk
  __shared__ float dsm[32 * 33];                   // dots, then attn (in-place)
  __shared__ float wred[4 * 32];
  const int t = threadIdx.x;
  const int jt = blockIdx.x;   // 0..15
  const int b = blockIdx.y;    // 0..63
  const long j0 = (long)jt * 256;

#pragma unroll
  for (int i = 0; i < 8; ++i) qs[i * 256 + t] = qin[b * 2048 + i * 256 + t];

  const int jq = t & 15, hp = (t >> 4) & 3, iq2 = t >> 6;   // dots
  const int sc = t >> 3, sp = t & 7;                        // softmax
  const int ivq = t >> 6, hd4 = t & 63, hh = hd4 >> 4;      // PV
  float rs0 = 0, rs1 = 0, rs2 = 0, rs3 = 0;
  f32x4 accu0 = (f32x4){0.f, 0.f, 0.f, 0.f};
  f32x4 accu1 = (f32x4){0.f, 0.f, 0.f, 0.f};
  f32x4 accsv = (f32x4){0.f, 0.f, 0.f, 0.f};

  for (int ch = 0; ch < 8; ++ch) {
    __syncthreads();  // protect ks/dsm from previous chunk readers (and qs, ch=0)
    // stage K chunk [32 j][256 d] bf16, XOR-swizzled rows
#pragma unroll
    for (int p = 0; p < 4; ++p) {
      const int idx = p * 256 + t;
      const int j = idx >> 5, c16 = idx & 31;
      const uint4 val =
          *(const uint4*)(Kb + ((long)b * 4096 + j0 + ch * 32 + j) * 256 + c16 * 8);
      *(uint4*)((char*)ks + j * 512 + ((c16 * 16) ^ ((j & 7) << 4))) = val;
    }
    __syncthreads();
    // dots: thread covers i = {2*iq2, 2*iq2+1}, h=hp, j = {jq, jq+16}
    float a00 = 0, a01 = 0, a10 = 0, a11 = 0;
#pragma unroll
    for (int g = 0; g < 8; ++g) {
      const float4 qa0 = *(const float4*)(qs + (iq2 * 2 + 0) * 256 + hp * 64 + g * 8);
      const float4 qb0 = *(const float4*)(qs + (iq2 * 2 + 0) * 256 + hp * 64 + g * 8 + 4);
      const float4 qa1 = *(const float4*)(qs + (iq2 * 2 + 1) * 256 + hp * 64 + g * 8);
      const float4 qb1 = *(const float4*)(qs + (iq2 * 2 + 1) * 256 + hp * 64 + g * 8 + 4);
#pragma unroll
      for (int jj = 0; jj < 2; ++jj) {
        const int j = jq + jj * 16;
        const uint4 kv = *(const uint4*)((const char*)ks + j * 512 +
                                         ((((hp * 8 + g) << 4)) ^ ((j & 7) << 4)));
        const float k0 = bflo(kv.x), k1 = bfhi(kv.x), k2 = bflo(kv.y), k3 = bfhi(kv.y);
        const float k4 = bflo(kv.z), k5 = bfhi(kv.z), k6 = bflo(kv.w), k7 = bfhi(kv.w);
        const float d0 = qa0.x * k0 + qa0.y * k1 + qa0.z * k2 + qa0.w * k3 +
                         qb0.x * k4 + qb0.y * k5 + qb0.z * k6 + qb0.w * k7;
        const float d1 = qa1.x * k0 + qa1.y * k1 + qa1.z * k2 + qa1.w * k3 +
                         qb1.x * k4 + qb1.y * k5 + qb1.z * k6 + qb1.w * k7;
        if (jj == 0) { a00 += d0; a10 += d1; } else { a01 += d0; a11 += d1; }
      }
    }
    dsm[jq * 33 + (iq2 * 2 + 0) * 4 + hp] = a00 * 0.125f;
    dsm[(jq + 16) * 33 + (iq2 * 2 + 0) * 4 + hp] = a01 * 0.125f;
    dsm[jq * 33 + (iq2 * 2 + 1) * 4 + hp] = a10 * 0.125f;
    dsm[(jq + 16) * 33 + (iq2 * 2 + 1) * 4 + hp] = a11 * 0.125f;
    __syncthreads();
    // inverted softmax: column sc over 32 (i,h); 8 threads/col, 4 vals each
    {
      float v0 = dsm[sc * 33 + sp * 4 + 0];
      float v1 = dsm[sc * 33 + sp * 4 + 1];
      float v2 = dsm[sc * 33 + sp * 4 + 2];
      float v3 = dsm[sc * 33 + sp * 4 + 3];
      float mx = fmaxf(fmaxf(v0, v1), fmaxf(v2, v3));
      mx = fmaxf(mx, __shfl_xor(mx, 1));
      mx = fmaxf(mx, __shfl_xor(mx, 2));
      mx = fmaxf(mx, __shfl_xor(mx, 4));
      v0 = __expf(v0 - mx); v1 = __expf(v1 - mx);
      v2 = __expf(v2 - mx); v3 = __expf(v3 - mx);
      float sum = v0 + v1 + v2 + v3;
      sum += __shfl_xor(sum, 1);
      sum += __shfl_xor(sum, 2);
      sum += __shfl_xor(sum, 4);
      const float inv = 1.f / sum;
      v0 *= inv; v1 *= inv; v2 *= inv; v3 *= inv;
      dsm[sc * 33 + sp * 4 + 0] = v0;
      dsm[sc * 33 + sp * 4 + 1] = v1;
      dsm[sc * 33 + sp * 4 + 2] = v2;
      dsm[sc * 33 + sp * 4 + 3] = v3;
      rs0 += v0; rs1 += v1; rs2 += v2; rs3 += v3;
      if (LAST)
        attn_out[((long)(b * 8 + sp)) * 4096 + j0 + ch * 32 + sc] =
            (v0 + v1 + v2 + v3) * 0.25f;
    }
    __syncthreads();
    // PV: thread owns d = hd4*4..+3, i = {ivq, ivq+4}; V streamed from global
    const unsigned short* vp =
        Vb + ((long)b * 4096 + j0 + ch * 32) * 256 + hd4 * 4;
#pragma unroll 8
    for (int j = 0; j < 32; ++j) {
      const uint2 vv = *(const uint2*)(vp + (long)j * 256);
      const float f0 = bflo(vv.x), f1 = bfhi(vv.x), f2 = bflo(vv.y), f3 = bfhi(vv.y);
      const float a0 = dsm[j * 33 + ivq * 4 + hh];
      const float a1 = dsm[j * 33 + (ivq + 4) * 4 + hh];
      accu0.x += a0 * f0; accu0.y += a0 * f1; accu0.z += a0 * f2; accu0.w += a0 * f3;
      accu1.x += a1 * f0; accu1.y += a1 * f1; accu1.z += a1 * f2; accu1.w += a1 * f3;
      if (ivq == 0) { accsv.x += f0; accsv.y += f1; accsv.z += f2; accsv.w += f3; }
    }
  }
  // write update partials
  const long ub = ((long)(jt * 64 + b)) * 8;
  *(f32x4*)(upart + (ub + ivq) * 256 + hd4 * 4) = accu0;
  *(f32x4*)(upart + (ub + ivq + 4) * 256 + hd4 * 4) = accu1;
  if (ivq == 0) *(f32x4*)(svpart + ((long)(jt * 64 + b)) * 256 + hd4 * 4) = accsv;
  // rowsum partials: reduce over the wave's 8 columns, then across waves
  rs0 += __shfl_xor(rs0, 8); rs0 += __shfl_xor(rs0, 16); rs0 += __shfl_xor(rs0, 32);
  rs1 += __shfl_xor(rs1, 8); rs1 += __shfl_xor(rs1, 16); rs1 += __shfl_xor(rs1, 32);
  rs2 += __shfl_xor(rs2, 8); rs2 += __shfl_xor(rs2, 16); rs2 += __shfl_xor(rs2, 32);
  rs3 += __shfl_xor(rs3, 8); rs3 += __shfl_xor(rs3, 16); rs3 += __shfl_xor(rs3, 32);
  if ((t & 63) < 8) {
    float* wr = wred + (t >> 6) * 32 + sp * 4;
    wr[0] = rs0; wr[1] = rs1; wr[2] = rs2; wr[3] = rs3;
  }
  __syncthreads();
  if (t < 32)
    rowsum_part[((long)(jt * 64 + b)) * 32 + t] =
        wred[t] + wred[32 + t] + wred[64 + t] + wred[96 + t];
}

// ---------------------------------------------------------------------------
// GRU cell; sums the 16 jt-partials, applies EPS renorm, torch gate order.
template <bool LAST>
__global__ __launch_bounds__(256) void k_gru(
    const float* __restrict__ upart, const float* __restrict__ svpart,
    const float* __restrict__ rowsum_part, const float* __restrict__ wihT,
    const float* __restrict__ whhT, const float* __restrict__ bih,
    const float* __restrict__ bhh, float* __restrict__ slots,
    float* __restrict__ dout) {
  __shared__ float xl[8 * 256];
  __shared__ float hl[8 * 256];
  __shared__ float rs[32];
  const int t = threadIdx.x;
  const int b = blockIdx.x;
  if (t < 32) {
    float s2 = 0.f;
#pragma unroll
    for (int p = 0; p < 16; ++p) s2 += rowsum_part[((long)(p * 64 + b)) * 32 + t];
    rs[t] = 1.f / (s2 + 4096.f * 1e-8f);
  }
  float svs = 0.f;
#pragma unroll
  for (int p = 0; p < 16; ++p) svs += svpart[((long)(p * 64 + b)) * 256 + t];
  __syncthreads();
  const int hcol = t >> 6;
#pragma unroll
  for (int r = 0; r < 8; ++r) {
    float pp = 0.f;
#pragma unroll
    for (int p = 0; p < 16; ++p)
      pp += upart[(((long)(p * 64 + b)) * 8 + r) * 256 + t];
    xl[r * 256 + t] = (pp + 1e-8f * svs) * rs[r * 4 + hcol];
    hl[r * 256 + t] = slots[b * 2048 + r * 256 + t];
  }
  __syncthreads();
  float air[8] = {}, aiz[8] = {}, ain[8] = {};
  float ahr[8] = {}, ahz[8] = {}, ahn[8] = {};
  for (int k = 0; k < 256; k += 4) {
    float wir[4], wiz[4], win_[4], whr[4], whz[4], whn[4];
#pragma unroll
    for (int u = 0; u < 4; ++u) {
      wir[u] = wihT[(k + u) * 768 + t];
      wiz[u] = wihT[(k + u) * 768 + 256 + t];
      win_[u] = wihT[(k + u) * 768 + 512 + t];
      whr[u] = whhT[(k + u) * 768 + t];
      whz[u] = whhT[(k + u) * 768 + 256 + t];
      whn[u] = whhT[(k + u) * 768 + 512 + t];
    }
#pragma unroll
    for (int r = 0; r < 8; ++r) {
      const float4 x4 = *(const float4*)(xl + r * 256 + k);
      const float4 h4 = *(const float4*)(hl + r * 256 + k);
      air[r] += x4.x * wir[0] + x4.y * wir[1] + x4.z * wir[2] + x4.w * wir[3];
      aiz[r] += x4.x * wiz[0] + x4.y * wiz[1] + x4.z * wiz[2] + x4.w * wiz[3];
      ain[r] += x4.x * win_[0] + x4.y * win_[1] + x4.z * win_[2] + x4.w * win_[3];
      ahr[r] += h4.x * whr[0] + h4.y * whr[1] + h4.z * whr[2] + h4.w * whr[3];
      ahz[r] += h4.x * whz[0] + h4.y * whz[1] + h4.z * whz[2] + h4.w * whz[3];
      ahn[r] += h4.x * whn[0] + h4.y * whn[1] + h4.z * whn[2] + h4.w * whn[3];
    }
  }
  const float bir = bih[t], biz = bih[256 + t], bin_ = bih[512 + t];
  const float bhr = bhh[t], bhz = bhh[256 + t], bhn = bhh[512 + t];
#pragma unroll
  for (int r = 0; r < 8; ++r) {
    const float rr = 1.f / (1.f + __expf(-(air[r] + bir + ahr[r] + bhr)));
    const float zz = 1.f / (1.f + __expf(-(aiz[r] + biz + ahz[r] + bhz)));
    const float nn2 = tanhf(ain[r] + bin_ + rr * (ahn[r] + bhn));
    const float hn = (1.f - zz) * nn2 + zz * hl[r * 256 + t];
    slots[b * 2048 + r * 256 + t] = hn;
    if (LAST) dout[b * 2048 + r * 256 + t] = hn;
  }
}

// ---------------------------------------------------------------------------
extern "C" void kernel_launch(void* const* d_in, const int* in_sizes, int n_in,
                              void* d_out, int out_size, void* d_ws,
                              size_t ws_size, hipStream_t stream) {
  const float* xin = (const float*)d_in[0];
  const float* cond = (const float*)d_in[1];
  const float* lnin_w = (const float*)d_in[2];
  const float* lnin_b = (const float*)d_in[3];
  const float* lns_w = (const float*)d_in[4];
  const float* lns_b = (const float*)d_in[5];
  const float* wq = (const float*)d_in[6];
  const float* wk = (const float*)d_in[7];
  const float* wv = (const float*)d_in[8];
  const float* gwih = (const float*)d_in[9];
  const float* gwhh = (const float*)d_in[10];
  const float* gbih = (const float*)d_in[11];
  const float* gbhh = (const float*)d_in[12];
  float* out = (float*)d_out;

  char* ws = (char*)d_ws;
  unsigned short* Kb = (unsigned short*)ws;  ws += 64l * 4096 * 256 * 2;   // 128MB
  unsigned short* Vb = (unsigned short*)ws;  ws += 64l * 4096 * 256 * 2;   // 128MB
  float2* stats = (float2*)ws;               ws += 262144l * 8;            // 2MB
  unsigned short* Wp = (unsigned short*)ws;  ws += 512l * 256 * 2;
  float* c12 = (float*)ws;                   ws += 1024l * 4;
  float* upart = (float*)ws;                 ws += 16l * 64 * 8 * 256 * 4; // 8MB
  float* svpart = (float*)ws;                ws += 16l * 64 * 256 * 4;     // 1MB
  float* rowsum_part = (float*)ws;           ws += 16l * 64 * 32 * 4;
  float* qbuf = (float*)ws;                  ws += 512l * 256 * 4;
  float* slots = (float*)ws;                 ws += 512l * 256 * 4;
  float* wihT = (float*)ws;                  ws += 256l * 768 * 4;
  float* whhT = (float*)ws;                  ws += 256l * 768 * 4;
  float* wqT = (float*)ws;                   ws += 256l * 256 * 4;
  // total ~283 MB

  hipMemcpyAsync(slots, cond, 512 * 256 * 4, hipMemcpyDeviceToDevice, stream);
  k_stats<<<65536, 256, 0, stream>>>(xin, stats);
  k_wprep<<<128, 256, 0, stream>>>(wk, wv, lnin_w, lnin_b, Wp, c12);
  k_transpose<<<1792, 256, 0, stream>>>(gwih, gwhh, wq, wihT, whhT, wqT);
  k_gemm<<<8192, 256, 0, stream>>>(xin, stats, Wp, c12, Kb, Vb);

  for (int it = 0; it < 3; ++it) {
    k_q<<<64, 256, 0, stream>>>(slots, lns_w, lns_b, wqT, qbuf);
    if (it == 2)
      k_att<true><<<dim3(16, 64), 256, 0, stream>>>(
          qbuf, Kb, Vb, upart, svpart, rowsum_part, out + 131072);
    else
      k_att<false><<<dim3(16, 64), 256, 0, stream>>>(
          qbuf, Kb, Vb, upart, svpart, rowsum_part, out + 131072);
    if (it == 2)
      k_gru<true><<<64, 256, 0, stream>>>(upart, svpart, rowsum_part, wihT,
                                          whhT, gbih, gbhh, slots, out);
    else
      k_gru<false><<<64, 256, 0, stream>>>(upart, svpart, rowsum_part, wihT,
                                           whhT, gbih, gbhh, slots, out);
  }
}